// Round 8
// baseline (17.633 us; speedup 1.0000x reference)
//
#include <hip/hip_runtime.h>

// Controlled target rotation, D=2, control=qubit0 (mask N/2), target=qubit1 (mask N/4).
// Output buffer: N float32 = REAL part of the complex64 state.
//   control clear (i < N/2): out[i] = xr[i]
//   control set:             out[i] = c*xr[i] + s*xi[i ^ (N/4)]
//   c = cos(a/2), s = sin(a/2), a = angle[0].
// Batch-8 per thread (8 chunks, stride 256), 1024 blocks. All loads issued
// before stores -> up to 16 independent 16B loads in flight per thread.

typedef float fvec4 __attribute__((ext_vector_type(4)));

__global__ __launch_bounds__(256) void crx_real_kernel(
    const float* __restrict__ xr,
    const float* __restrict__ xi,
    const float* __restrict__ angle,
    float* __restrict__ out,   // N float32 (real part)
    unsigned int n4)           // number of float4 chunks = N/4
{
    const unsigned int cmask4 = n4 >> 1;   // control-bit mask, float4 units
    const unsigned int tmask4 = n4 >> 2;   // target-bit mask, float4 units

    const fvec4* xr4 = reinterpret_cast<const fvec4*>(xr);
    const fvec4* xi4 = reinterpret_cast<const fvec4*>(xi);
    fvec4* out4 = reinterpret_cast<fvec4*>(out);

    // Each block covers 2048 consecutive chunks; thread t handles
    // base + k*256, k=0..7. Block range (2048 chunks) stays inside one
    // quarter (n4/4 = 2^19 chunks) -> control branch is block-uniform.
    unsigned int base = blockIdx.x * 2048u + threadIdx.x;

    fvec4 v[8];
    #pragma unroll
    for (int k = 0; k < 8; ++k)
        v[k] = xr4[base + (unsigned)k * 256u];

    if (base & cmask4) {   // upper half: rotate with partner imag
        fvec4 p[8];
        #pragma unroll
        for (int k = 0; k < 8; ++k)
            p[k] = xi4[(base + (unsigned)k * 256u) ^ tmask4];

        float half_a = 0.5f * angle[0];
        float s = sinf(half_a);
        float c = cosf(half_a);

        #pragma unroll
        for (int k = 0; k < 8; ++k)
            v[k] = c * v[k] + s * p[k];
    }

    #pragma unroll
    for (int k = 0; k < 8; ++k)
        __builtin_nontemporal_store(v[k], out4 + base + (unsigned)k * 256u);
}

extern "C" void kernel_launch(void* const* d_in, const int* in_sizes, int n_in,
                              void* d_out, int out_size, void* d_ws, size_t ws_size,
                              hipStream_t stream) {
    const float* xr    = (const float*)d_in[0];
    const float* xi    = (const float*)d_in[1];
    const float* angle = (const float*)d_in[2];
    float* out = (float*)d_out;

    unsigned int n = (unsigned int)in_sizes[0];   // N = 2^23 complex elements
    unsigned int n4 = n / 4u;                     // float4 chunks (2^21)
    unsigned int block = 256u;
    unsigned int grid = n4 / 2048u;               // exact cover: 1024 blocks
    crx_real_kernel<<<grid, block, 0, stream>>>(xr, xi, angle, out, n4);
}

// Round 9
// 17.142 us; speedup vs baseline: 1.0287x; 1.0287x over previous
//
#include <hip/hip_runtime.h>

// Controlled target rotation, D=2, control=qubit0 (mask N/2), target=qubit1 (mask N/4).
// Output buffer: N float32 = REAL part of the complex64 state.
//   control clear (i < N/2): out[i] = xr[i]
//   control set:             out[i] = c*xr[i] + s*xi[i ^ (N/4)]
//   c = cos(a/2), s = sin(a/2), a = angle[0].
// Best measured variant (round 7): batch-4 per thread, 2048 blocks, NT ld/st.
// Ladder: naive-f4 18.4 -> grid-stride+NT 17.7 -> batch-4 17.15 -> batch-8 17.6 (noise).
// Floor: 80 MiB forced cold-HBM traffic (~13.3 us @ 6.29 TB/s) + fixed replay overhead.

typedef float fvec4 __attribute__((ext_vector_type(4)));

__global__ __launch_bounds__(256) void crx_real_kernel(
    const float* __restrict__ xr,
    const float* __restrict__ xi,
    const float* __restrict__ angle,
    float* __restrict__ out,   // N float32 (real part)
    unsigned int n4)           // number of float4 chunks = N/4
{
    const unsigned int cmask4 = n4 >> 1;   // control-bit mask, float4 units
    const unsigned int tmask4 = n4 >> 2;   // target-bit mask, float4 units

    const fvec4* xr4 = reinterpret_cast<const fvec4*>(xr);
    const fvec4* xi4 = reinterpret_cast<const fvec4*>(xi);
    fvec4* out4 = reinterpret_cast<fvec4*>(out);

    // Each block covers 1024 consecutive chunks: thread t handles
    // base+0, +256, +512, +768. Block range stays inside one quarter
    // (quarter = n4/4 = 2^19 chunks) -> control branch is block-uniform.
    unsigned int base = blockIdx.x * 1024u + threadIdx.x;

    fvec4 v0 = __builtin_nontemporal_load(xr4 + base);
    fvec4 v1 = __builtin_nontemporal_load(xr4 + base + 256u);
    fvec4 v2 = __builtin_nontemporal_load(xr4 + base + 512u);
    fvec4 v3 = __builtin_nontemporal_load(xr4 + base + 768u);

    if (base & cmask4) {   // upper half: rotate with partner imag
        fvec4 p0 = __builtin_nontemporal_load(xi4 + ((base)          ^ tmask4));
        fvec4 p1 = __builtin_nontemporal_load(xi4 + ((base + 256u)   ^ tmask4));
        fvec4 p2 = __builtin_nontemporal_load(xi4 + ((base + 512u)   ^ tmask4));
        fvec4 p3 = __builtin_nontemporal_load(xi4 + ((base + 768u)   ^ tmask4));

        float half_a = 0.5f * angle[0];
        float s = sinf(half_a);
        float c = cosf(half_a);

        v0 = c * v0 + s * p0;
        v1 = c * v1 + s * p1;
        v2 = c * v2 + s * p2;
        v3 = c * v3 + s * p3;
    }

    __builtin_nontemporal_store(v0, out4 + base);
    __builtin_nontemporal_store(v1, out4 + base + 256u);
    __builtin_nontemporal_store(v2, out4 + base + 512u);
    __builtin_nontemporal_store(v3, out4 + base + 768u);
}

extern "C" void kernel_launch(void* const* d_in, const int* in_sizes, int n_in,
                              void* d_out, int out_size, void* d_ws, size_t ws_size,
                              hipStream_t stream) {
    const float* xr    = (const float*)d_in[0];
    const float* xi    = (const float*)d_in[1];
    const float* angle = (const float*)d_in[2];
    float* out = (float*)d_out;

    unsigned int n = (unsigned int)in_sizes[0];   // N = 2^23 complex elements
    unsigned int n4 = n / 4u;                     // float4 chunks (2^21)
    unsigned int block = 256u;
    unsigned int grid = n4 / 1024u;               // exact cover: 2048 blocks
    crx_real_kernel<<<grid, block, 0, stream>>>(xr, xi, angle, out, n4);
}